// Round 7
// baseline (112.256 us; speedup 1.0000x reference)
//
#include <hip/hip_runtime.h>
#include <hip/hip_bf16.h>

// Modulated conv2d (StyleGAN2) on MI355X.
// out[b,o] = rsig[b,o] * conv(s[b,:]*x[b,:], W*SCALE)   (shared weights)
// rsig[b,o] = 1/sqrt(sum_i s[b,i]^2 * wsq[o,i] + 1e-8)
// Conv as implicit GEMM: D[o][p] = sum_k Wb[o][k] * Xcl[p][k].
//
// R7: no split-K (merge kernel deleted). Grid 256 blocks = 1/CU, 4 waves,
// per-wave 64x128 (R6's proven good LDS:MFMA ratio), K=4608 = 72 tiles.
// Zero TLP at 1 wave/SIMD -> the vmcnt(0) drain would be fully exposed, so:
// TRIPLE-buffered LDS (144 KiB, whole CU available at 1 blk/CU), stage 2
// tiles ahead, per-iter counted vmcnt(12) + ONE s_barrier.
// Hazard audit: BAR(kt) separates iter kt-1's reads of buf[(kt-1)%3] from
// iter kt's stage into that same buffer; each wave's ds_reads are complete
// before it reaches BAR (its MFMAs consumed them via lgkmcnt).

typedef __attribute__((ext_vector_type(4))) float f32x4;
typedef __attribute__((ext_vector_type(8))) short bf16x8;

#define NB    16
#define CIN   512
#define COUT  512
#define KTOT  4608           // CIN * 9
#define NPIX  (NB * 32 * 32) // 16384
#define KTILES 72
#define BUFBYTES 49152       // A 16KB + B 32KB per buffer

#define WAITV12() asm volatile("s_waitcnt vmcnt(12)" ::: "memory")
#define WAITV0()  asm volatile("s_waitcnt vmcnt(0)" ::: "memory")
#define FENCE()   asm volatile("" ::: "memory")
#define BAR()     { FENCE(); __builtin_amdgcn_s_barrier(); FENCE(); }

__device__ __forceinline__ void gload_lds16(const void* g, void* l) {
  __builtin_amdgcn_global_load_lds(
      (__attribute__((address_space(1))) void*)(g),
      (__attribute__((address_space(3))) void*)(l), 16, 0, 0);
}

// ---- kernel 1: pack weights (bf16, [o][tap*512+ci]) + wsq ----
__global__ __launch_bounds__(256) void pack_w_kernel(
    const float* __restrict__ w, __hip_bfloat16* __restrict__ wB,
    float* __restrict__ wsq) {
  const int idx = blockIdx.x * 256 + threadIdx.x;   // = o*512 + ci
  const int o = idx >> 9, ci = idx & 511;
  const float* wp = w + (size_t)idx * 9;
  const float WSCALE = 0.014731391274719739f;       // 1/sqrt(512*9)
  float sum = 0.f;
#pragma unroll
  for (int t = 0; t < 9; ++t) {
    float v = wp[t] * WSCALE;
    sum += v * v;
    wB[(size_t)o * KTOT + t * 512 + ci] = __float2bfloat16(v);
  }
  wsq[idx] = sum;
}

// ---- kernel 2: rsig[b][o], one wave per (b,o) ----
__global__ __launch_bounds__(256) void calc_rsig_kernel(
    const float* __restrict__ s, const float* __restrict__ wsq,
    float* __restrict__ rsig) {
  const int wid = blockIdx.x * 4 + (threadIdx.x >> 6); // b*512 + o
  const int lane = threadIdx.x & 63;
  const int b = wid >> 9, o = wid & 511;
  const float* sp = s + b * 512;
  const float* wp = wsq + o * 512;
  float sum = 0.f;
#pragma unroll
  for (int i = 0; i < 8; ++i) {
    float sv = sp[lane + i * 64];
    sum += sv * sv * wp[lane + i * 64];
  }
#pragma unroll
  for (int off = 32; off > 0; off >>= 1) sum += __shfl_down(sum, off, 64);
  if (lane == 0) rsig[wid] = 1.0f / sqrtf(sum + 1e-8f);
}

// ---- kernel 3: modulate + NCHW -> padded channels-last bf16 ----
__global__ __launch_bounds__(256) void modulate_kernel(
    const float* __restrict__ x, const float* __restrict__ s,
    __hip_bfloat16* __restrict__ xpad) {
  const int by = blockIdx.x;            // b*32 + y
  const int b = by >> 5, y = by & 31;
  __shared__ __attribute__((aligned(16))) __hip_bfloat16 tile[32][72];
  const int tid = threadIdx.x;
  const int xc = tid & 31;
  const int cr0 = tid >> 5;
  const float* xrow = x + ((size_t)b * 512 * 32 + y) * 32;
  const float* sb = s + b * 512;
  __hip_bfloat16* orow = xpad + (size_t)((b * 34 + y + 1) * 34) * 512;

  for (int ci0 = 0; ci0 < 512; ci0 += 64) {
#pragma unroll
    for (int r = 0; r < 8; ++r) {
      const int cir = r * 8 + cr0;
      const int ci = ci0 + cir;
      float v = xrow[(size_t)ci * 1024 + xc] * sb[ci];
      tile[xc][cir] = __float2bfloat16(v);
    }
    __syncthreads();
    const int xcw = tid >> 3, vec = tid & 7;
    bf16x8 v = *(const bf16x8*)&tile[xcw][vec * 8];
    *(bf16x8*)(orow + (size_t)(xcw + 1) * 512 + ci0 + vec * 8) = v;
    __syncthreads();
  }
}

// ---- kernel 4: implicit-GEMM conv, full-K, triple-buffered counted-vmcnt ----
// Block: 128 cout x 256 pix, 256 thr, 4 waves 2Mx2N, per-wave 64x128
// (acc 4x8). LDS buffer i (i=0..2) at ldsc+i*49152: A[128][64] then B[256][64],
// row-major 128B rows, XOR swizzle byte^=((row&7)<<4) on staging source chunk
// + ds_read (rule 21; 0 conflicts measured R1-R6).
__global__ __launch_bounds__(256, 1) void conv_gemm_kernel(
    const __hip_bfloat16* __restrict__ wB,    // [512][4608]
    const __hip_bfloat16* __restrict__ xpad,  // [16][34][34][512]
    const float* __restrict__ rsig,           // [16][512]
    float* __restrict__ out) {                // [16][512][32][32] f32
  extern __shared__ __attribute__((aligned(16))) char ldsc[];

  const int tid = threadIdx.x;
  const int wv = tid >> 6, lane = tid & 63, l15 = lane & 15;
  const int bo0 = blockIdx.y << 7;   // cout block (128)
  const int bp0 = blockIdx.x << 8;   // pixel block (256; 256 | 1024 per image)
  const int bimg = blockIdx.x >> 2;
  const int wr = wv >> 1, wc = wv & 1;

  // Staging source offsets (pre-swizzled chunk within row; rule 21).
  int gA[4];   // + kt*64 per tile
#pragma unroll
  for (int r = 0; r < 4; ++r) {
    const int c = r * 256 + tid, row = c >> 3, sc = (c & 7) ^ (row & 7);
    gA[r] = (bo0 + row) * KTOT + sc * 8;
  }
  int gB[8];   // + tapoff*512 + ci0 per tile
#pragma unroll
  for (int r = 0; r < 8; ++r) {
    const int c = r * 256 + tid, row = c >> 3, sc = (c & 7) ^ (row & 7);
    const int p = bp0 + row, b = p >> 10, rem = p & 1023, y = rem >> 5,
              xx = rem & 31;
    gB[r] = ((b * 34 + y) * 34 + xx) * 512 + sc * 8;
  }

  auto stage = [&](int kt) {
    char* base = ldsc + (kt % 3) * BUFBYTES;
    const int tap = kt >> 3;
    const int xoff = (tap + 31 * (tap / 3)) * 512 + ((kt & 7) << 6);
#pragma unroll
    for (int r = 0; r < 4; ++r)
      gload_lds16(wB + (size_t)(gA[r] + (kt << 6)),
                  base + (r * 256 + tid) * 16);
#pragma unroll
    for (int r = 0; r < 8; ++r)
      gload_lds16(xpad + (size_t)(gB[r] + xoff),
                  base + 16384 + (r * 256 + tid) * 16);
  };

  f32x4 acc[4][8];
#pragma unroll
  for (int mi = 0; mi < 4; ++mi)
#pragma unroll
    for (int ni = 0; ni < 8; ++ni) acc[mi][ni] = f32x4{0.f, 0.f, 0.f, 0.f};

  const int kb0 = (lane >> 4) << 4;   // byte base of this lane's k-slot

  // Prologue: stage tiles 0,1 (12 vmem instr/wave each).
  stage(0);
  stage(1);

#pragma unroll 1
  for (int kt = 0; kt < KTILES; ++kt) {
    // Wait: tile kt's 12 loads done (newest 12 = tile kt+1's stay in flight).
    if (kt < KTILES - 1) { WAITV12(); } else { WAITV0(); }
    BAR();   // all waves' waits done; also fences iter kt-1 reads vs stage below
    if (kt + 2 < KTILES) stage(kt + 2);   // overwrites buf read at iter kt-1

    const char* bufA = ldsc + (kt % 3) * BUFBYTES;
    const char* bufB = bufA + 16384;

    bf16x8 af[4][2];
#pragma unroll
    for (int mi = 0; mi < 4; ++mi) {
      const int row = (wr << 6) + (mi << 4) + l15;
      const int swz = (row & 7) << 4;
      af[mi][0] = *(const bf16x8*)(bufA + row * 128 + (kb0 ^ swz));
      af[mi][1] = *(const bf16x8*)(bufA + row * 128 + ((64 | kb0) ^ swz));
    }
    {
      bf16x8 bv[8];
#pragma unroll
      for (int ni = 0; ni < 8; ++ni) {
        const int row = (wc << 7) + (ni << 4) + l15;
        bv[ni] = *(const bf16x8*)(bufB + row * 128 + (kb0 ^ ((row & 7) << 4)));
      }
#pragma unroll
      for (int mi = 0; mi < 4; ++mi)
#pragma unroll
        for (int ni = 0; ni < 8; ++ni)
          acc[mi][ni] = __builtin_amdgcn_mfma_f32_16x16x32_bf16(
              af[mi][0], bv[ni], acc[mi][ni], 0, 0, 0);
    }
    {
      bf16x8 bv[8];
#pragma unroll
      for (int ni = 0; ni < 8; ++ni) {
        const int row = (wc << 7) + (ni << 4) + l15;
        bv[ni] = *(const bf16x8*)(bufB + row * 128 +
                                  ((64 | kb0) ^ ((row & 7) << 4)));
      }
#pragma unroll
      for (int mi = 0; mi < 4; ++mi)
#pragma unroll
        for (int ni = 0; ni < 8; ++ni)
          acc[mi][ni] = __builtin_amdgcn_mfma_f32_16x16x32_bf16(
              af[mi][1], bv[ni], acc[mi][ni], 0, 0, 0);
    }
  }

  // Epilogue: D[o][p] * rsig[b][o] -> f32 out.
  // C/D: col(=p)=lane&15, row(=o)=(lane>>4)*4+r
#pragma unroll
  for (int mi = 0; mi < 4; ++mi) {
    const int o = bo0 + (wr << 6) + (mi << 4) + ((lane >> 4) << 2);
    const f32x4 rs = *(const f32x4*)(rsig + (bimg << 9) + o);
#pragma unroll
    for (int ni = 0; ni < 8; ++ni) {
      const int p = bp0 + (wc << 7) + (ni << 4) + l15;
      const int prem = p & 1023;
#pragma unroll
      for (int r = 0; r < 4; ++r)
        out[((size_t)(bimg << 9) + o + r) * 1024 + prem] =
            acc[mi][ni][r] * rs[r];
    }
  }
}

extern "C" void kernel_launch(void* const* d_in, const int* in_sizes, int n_in,
                              void* d_out, int out_size, void* d_ws,
                              size_t ws_size, hipStream_t stream) {
  const float* x = (const float*)d_in[0];   // [16,512,32,32]
  const float* s = (const float*)d_in[1];   // [16,512]
  const float* w = (const float*)d_in[2];   // [512,512,3,3]
  float* out = (float*)d_out;               // [16,512,32,32] f32

  char* ws = (char*)d_ws;
  const size_t xpad_bytes = (size_t)NB * 34 * 34 * 512 * 2;  // 18,939,904
  const size_t wB_bytes = (size_t)COUT * KTOT * 2;           //  4,718,592
  const size_t wsq_bytes = (size_t)COUT * CIN * 4;           //  1,048,576
  __hip_bfloat16* xpad = (__hip_bfloat16*)ws;
  __hip_bfloat16* wB = (__hip_bfloat16*)(ws + xpad_bytes);
  float* wsq = (float*)(ws + xpad_bytes + wB_bytes);
  float* rsig = (float*)(ws + xpad_bytes + wB_bytes + wsq_bytes);

  const int lds_bytes = 3 * BUFBYTES;   // 147456 B = 144 KiB
  hipFuncSetAttribute((const void*)conv_gemm_kernel,
                      hipFuncAttributeMaxDynamicSharedMemorySize, lds_bytes);

  hipMemsetAsync(xpad, 0, xpad_bytes, stream);  // zero halo (capturable)
  pack_w_kernel<<<(COUT * CIN) / 256, 256, 0, stream>>>(w, wB, wsq);
  modulate_kernel<<<NB * 32, 256, 0, stream>>>(x, s, xpad);
  calc_rsig_kernel<<<(NB * COUT) / 4, 256, 0, stream>>>(s, wsq, rsig);
  conv_gemm_kernel<<<dim3(NPIX / 256, COUT / 128), 256, lds_bytes, stream>>>(
      wB, xpad, rsig, out);
}

// Round 8
// 102.996 us; speedup vs baseline: 1.0899x; 1.0899x over previous
//
#include <hip/hip_runtime.h>
#include <hip/hip_bf16.h>

// Modulated conv2d (StyleGAN2) on MI355X.
// out[b,o] = rsig[b,o] * conv(s[b,:]*x[b,:], W*SCALE)   (shared weights)
// rsig[b,o] = 1/sqrt(sum_i s[b,i]^2 * wsq[o,i] + 1e-8)
// Conv as implicit GEMM: D[o][p] = sum_k Wb[o][k] * Xcl[p][k].
//
// R8: 512-thr block (8 waves = 2/SIMD, TLP restored vs R7) with wave-level
// K-split 2Mx2Nx2K (per-wave 64x128 over its K32-half -> LDS reads HALVED
// vs R6: 96KB/tile/CU), full K in-block (merge kernel + partial writes
// deleted). Triple-buffered LDS 144KB (1 blk/CU), counted vmcnt(6) + one
// s_barrier per K-tile (R7's verified schedule), K-merge via LDS at the end
// (R5's field-verified code). Model: LDS ~1600cyc vs MFMA 1242cyc per tile.

typedef __attribute__((ext_vector_type(4))) float f32x4;
typedef __attribute__((ext_vector_type(8))) short bf16x8;

#define NB    16
#define CIN   512
#define COUT  512
#define KTOT  4608           // CIN * 9
#define NPIX  (NB * 32 * 32) // 16384
#define KTILES 72
#define BUFBYTES 49152       // A 16KB + B 32KB per buffer

#define WAITV6() asm volatile("s_waitcnt vmcnt(6)" ::: "memory")
#define WAITV0() asm volatile("s_waitcnt vmcnt(0)" ::: "memory")
#define FENCE()  asm volatile("" ::: "memory")
#define BAR()    { FENCE(); __builtin_amdgcn_s_barrier(); FENCE(); }

__device__ __forceinline__ void gload_lds16(const void* g, void* l) {
  __builtin_amdgcn_global_load_lds(
      (__attribute__((address_space(1))) void*)(g),
      (__attribute__((address_space(3))) void*)(l), 16, 0, 0);
}

// ---- kernel 1: pack weights (bf16, [o][tap*512+ci]) + wsq ----
__global__ __launch_bounds__(256) void pack_w_kernel(
    const float* __restrict__ w, __hip_bfloat16* __restrict__ wB,
    float* __restrict__ wsq) {
  const int idx = blockIdx.x * 256 + threadIdx.x;   // = o*512 + ci
  const int o = idx >> 9, ci = idx & 511;
  const float* wp = w + (size_t)idx * 9;
  const float WSCALE = 0.014731391274719739f;       // 1/sqrt(512*9)
  float sum = 0.f;
#pragma unroll
  for (int t = 0; t < 9; ++t) {
    float v = wp[t] * WSCALE;
    sum += v * v;
    wB[(size_t)o * KTOT + t * 512 + ci] = __float2bfloat16(v);
  }
  wsq[idx] = sum;
}

// ---- kernel 2: rsig[b][o], one wave per (b,o) ----
__global__ __launch_bounds__(256) void calc_rsig_kernel(
    const float* __restrict__ s, const float* __restrict__ wsq,
    float* __restrict__ rsig) {
  const int wid = blockIdx.x * 4 + (threadIdx.x >> 6); // b*512 + o
  const int lane = threadIdx.x & 63;
  const int b = wid >> 9, o = wid & 511;
  const float* sp = s + b * 512;
  const float* wp = wsq + o * 512;
  float sum = 0.f;
#pragma unroll
  for (int i = 0; i < 8; ++i) {
    float sv = sp[lane + i * 64];
    sum += sv * sv * wp[lane + i * 64];
  }
#pragma unroll
  for (int off = 32; off > 0; off >>= 1) sum += __shfl_down(sum, off, 64);
  if (lane == 0) rsig[wid] = 1.0f / sqrtf(sum + 1e-8f);
}

// ---- kernel 3: modulate + NCHW -> padded channels-last bf16 ----
__global__ __launch_bounds__(256) void modulate_kernel(
    const float* __restrict__ x, const float* __restrict__ s,
    __hip_bfloat16* __restrict__ xpad) {
  const int by = blockIdx.x;            // b*32 + y
  const int b = by >> 5, y = by & 31;
  __shared__ __attribute__((aligned(16))) __hip_bfloat16 tile[32][72];
  const int tid = threadIdx.x;
  const int xc = tid & 31;
  const int cr0 = tid >> 5;
  const float* xrow = x + ((size_t)b * 512 * 32 + y) * 32;
  const float* sb = s + b * 512;
  __hip_bfloat16* orow = xpad + (size_t)((b * 34 + y + 1) * 34) * 512;

  for (int ci0 = 0; ci0 < 512; ci0 += 64) {
#pragma unroll
    for (int r = 0; r < 8; ++r) {
      const int cir = r * 8 + cr0;
      const int ci = ci0 + cir;
      float v = xrow[(size_t)ci * 1024 + xc] * sb[ci];
      tile[xc][cir] = __float2bfloat16(v);
    }
    __syncthreads();
    const int xcw = tid >> 3, vec = tid & 7;
    bf16x8 v = *(const bf16x8*)&tile[xcw][vec * 8];
    *(bf16x8*)(orow + (size_t)(xcw + 1) * 512 + ci0 + vec * 8) = v;
    __syncthreads();
  }
}

// ---- kernel 4: implicit-GEMM conv, 8 waves 2Mx2Nx2K, triple-buffered ----
// Block: 128 cout x 256 pix, K=4608 (72 tiles). LDS buffer i (0..2) at
// ldsc+i*49152: A[128][64] then B[256][64], row-major 128B rows, XOR swizzle
// byte^=((row&7)<<4) on staging source chunk + ds_read (rule 21; 0 conflicts
// R1-R7). Wave (wr,wc,wk) computes out[wr*64+ : wc*128+] over k-half wk.
__global__ __launch_bounds__(512, 1) void conv_gemm_kernel(
    const __hip_bfloat16* __restrict__ wB,    // [512][4608]
    const __hip_bfloat16* __restrict__ xpad,  // [16][34][34][512]
    const float* __restrict__ rsig,           // [16][512]
    float* __restrict__ out) {                // [16][512][32][32] f32
  extern __shared__ __attribute__((aligned(16))) char ldsc[];

  const int tid = threadIdx.x;
  const int wv = tid >> 6, lane = tid & 63, l15 = lane & 15;
  const int bo0 = blockIdx.y << 7;   // cout block (128)
  const int bp0 = blockIdx.x << 8;   // pixel block (256; 256 | 1024 per image)
  const int bimg = blockIdx.x >> 2;
  const int wr = wv >> 2, wc = (wv >> 1) & 1, wk = wv & 1;

  // Staging source offsets (pre-swizzled chunk within row; rule 21).
  int gA[2];   // + kt*64 per tile
#pragma unroll
  for (int r = 0; r < 2; ++r) {
    const int c = r * 512 + tid, row = c >> 3, sc = (c & 7) ^ (row & 7);
    gA[r] = (bo0 + row) * KTOT + sc * 8;
  }
  int gB[4];   // + tapoff*512 + ci0 per tile
#pragma unroll
  for (int r = 0; r < 4; ++r) {
    const int c = r * 512 + tid, row = c >> 3, sc = (c & 7) ^ (row & 7);
    const int p = bp0 + row, b = p >> 10, rem = p & 1023, y = rem >> 5,
              xx = rem & 31;
    gB[r] = ((b * 34 + y) * 34 + xx) * 512 + sc * 8;
  }

  auto stage = [&](int kt) {   // 6 x 16B per thread = 48KB
    char* base = ldsc + (kt % 3) * BUFBYTES;
    const int tap = kt >> 3;
    const int xoff = (tap + 31 * (tap / 3)) * 512 + ((kt & 7) << 6);
#pragma unroll
    for (int r = 0; r < 2; ++r)
      gload_lds16(wB + (size_t)(gA[r] + (kt << 6)),
                  base + (r * 512 + tid) * 16);
#pragma unroll
    for (int r = 0; r < 4; ++r)
      gload_lds16(xpad + (size_t)(gB[r] + xoff),
                  base + 16384 + (r * 512 + tid) * 16);
  };

  f32x4 acc[4][8];
#pragma unroll
  for (int mi = 0; mi < 4; ++mi)
#pragma unroll
    for (int ni = 0; ni < 8; ++ni) acc[mi][ni] = f32x4{0.f, 0.f, 0.f, 0.f};

  const int kb0 = (wk << 6) | ((lane >> 4) << 4);  // this wave's k-half slot

  // Prologue: stage tiles 0,1 (6 vmem instr/thread each).
  stage(0);
  stage(1);

#pragma unroll 1
  for (int kt = 0; kt < KTILES; ++kt) {
    // At loop top: outstanding = tile kt (6) + tile kt+1 (6, if staged).
    if (kt < KTILES - 1) { WAITV6(); } else { WAITV0(); }
    BAR();   // everyone's tile-kt data visible; fences iter kt-1 reads too
    if (kt + 2 < KTILES) stage(kt + 2);   // overwrites buf read at iter kt-1

    const char* bufA = ldsc + (kt % 3) * BUFBYTES;
    const char* bufB = bufA + 16384;

    bf16x8 af[4], bv[8];
#pragma unroll
    for (int mi = 0; mi < 4; ++mi) {
      const int row = (wr << 6) + (mi << 4) + l15;
      af[mi] = *(const bf16x8*)(bufA + row * 128 + (kb0 ^ ((row & 7) << 4)));
    }
#pragma unroll
    for (int ni = 0; ni < 8; ++ni) {
      const int row = (wc << 7) + (ni << 4) + l15;
      bv[ni] = *(const bf16x8*)(bufB + row * 128 + (kb0 ^ ((row & 7) << 4)));
    }
    __builtin_amdgcn_s_setprio(1);
#pragma unroll
    for (int mi = 0; mi < 4; ++mi)
#pragma unroll
      for (int ni = 0; ni < 8; ++ni)
        acc[mi][ni] = __builtin_amdgcn_mfma_f32_16x16x32_bf16(
            af[mi], bv[ni], acc[mi][ni], 0, 0, 0);
    __builtin_amdgcn_s_setprio(0);
  }

  // ---- K-merge via LDS (R5's verified pattern): wk=1 parks, wk=0 adds ----
  __syncthreads();   // all tiles done; LDS free for reuse
  const int slot = ((wr << 1) | wc) << 15;   // 32KB per (wr,wc) pair
  if (wk) {
#pragma unroll
    for (int mi = 0; mi < 4; ++mi)
#pragma unroll
      for (int ni = 0; ni < 8; ++ni)
        *(f32x4*)(ldsc + slot + (((mi << 3) | ni) << 10) + (lane << 4)) =
            acc[mi][ni];
  }
  __syncthreads();
  if (!wk) {
    // Epilogue: D[o][p] * rsig[b][o]. C/D: col=lane&15, row=(lane>>4)*4+r
#pragma unroll
    for (int mi = 0; mi < 4; ++mi) {
      const int o = bo0 + (wr << 6) + (mi << 4) + ((lane >> 4) << 2);
      const f32x4 rs = *(const f32x4*)(rsig + (bimg << 9) + o);
#pragma unroll
      for (int ni = 0; ni < 8; ++ni) {
        const f32x4 o4 =
            *(const f32x4*)(ldsc + slot + (((mi << 3) | ni) << 10) + (lane << 4));
        const f32x4 a = acc[mi][ni] + o4;
        const int p = bp0 + (wc << 7) + (ni << 4) + l15;
        const int prem = p & 1023;
#pragma unroll
        for (int r = 0; r < 4; ++r)
          out[((size_t)(bimg << 9) + o + r) * 1024 + prem] = a[r] * rs[r];
      }
    }
  }
}

extern "C" void kernel_launch(void* const* d_in, const int* in_sizes, int n_in,
                              void* d_out, int out_size, void* d_ws,
                              size_t ws_size, hipStream_t stream) {
  const float* x = (const float*)d_in[0];   // [16,512,32,32]
  const float* s = (const float*)d_in[1];   // [16,512]
  const float* w = (const float*)d_in[2];   // [512,512,3,3]
  float* out = (float*)d_out;               // [16,512,32,32] f32

  char* ws = (char*)d_ws;
  const size_t xpad_bytes = (size_t)NB * 34 * 34 * 512 * 2;  // 18,939,904
  const size_t wB_bytes = (size_t)COUT * KTOT * 2;           //  4,718,592
  const size_t wsq_bytes = (size_t)COUT * CIN * 4;           //  1,048,576
  __hip_bfloat16* xpad = (__hip_bfloat16*)ws;
  __hip_bfloat16* wB = (__hip_bfloat16*)(ws + xpad_bytes);
  float* wsq = (float*)(ws + xpad_bytes + wB_bytes);
  float* rsig = (float*)(ws + xpad_bytes + wB_bytes + wsq_bytes);

  const int lds_bytes = 3 * BUFBYTES;   // 147456 B = 144 KiB
  hipFuncSetAttribute((const void*)conv_gemm_kernel,
                      hipFuncAttributeMaxDynamicSharedMemorySize, lds_bytes);

  hipMemsetAsync(xpad, 0, xpad_bytes, stream);  // zero halo (capturable)
  pack_w_kernel<<<(COUT * CIN) / 256, 256, 0, stream>>>(w, wB, wsq);
  modulate_kernel<<<NB * 32, 256, 0, stream>>>(x, s, xpad);
  calc_rsig_kernel<<<(NB * COUT) / 4, 256, 0, stream>>>(s, wsq, rsig);
  conv_gemm_kernel<<<dim3(NPIX / 256, COUT / 128), 512, lds_bytes, stream>>>(
      wB, xpad, rsig, out);
}